// Round 2
// baseline (729.436 us; speedup 1.0000x reference)
//
#include <hip/hip_runtime.h>
#include <cstdint>

#define B_ 64
#define L_ 512
#define H_ 1024
#define D_ 2048

typedef __attribute__((ext_vector_type(8))) short short8;
typedef __attribute__((ext_vector_type(4))) float f32x4;
typedef unsigned int u32;

static __device__ __forceinline__ float bf2f(u32 lo16) {
    u32 u = lo16 << 16;
    return __builtin_bit_cast(float, u);
}
static __device__ __forceinline__ unsigned short f2bf(float f) {
    u32 u = __builtin_bit_cast(u32, f);
    u += 0x7fffu + ((u >> 16) & 1u);
    return (unsigned short)(u >> 16);
}
static __device__ __forceinline__ u32 pk(float x, float y) {
    return (u32)f2bf(x) | ((u32)f2bf(y) << 16);
}
static __device__ __forceinline__ float fast_pexp(float u) {
    u = fminf(15.f, fmaxf(-15.f, u));
    float ex = __expf(2.f * u);
    float th = (ex - 1.f) / (ex + 1.f);
    return __expf(th);
}
// async global->LDS, 16B per lane; lds base must be wave-uniform (HW: base + lane*16)
static __device__ __forceinline__ void gload_lds16(const unsigned short* g, unsigned short* l) {
    __builtin_amdgcn_global_load_lds((const __attribute__((address_space(1))) u32*)g,
                                     (__attribute__((address_space(3))) u32*)l, 16, 0, 0);
}

// ---------------- s[b,h] = sum_l h_state[b,l,h] ----------------
__global__ __launch_bounds__(256) void k_s(const float* __restrict__ h, float* __restrict__ s) {
    int t = blockIdx.x * 256 + threadIdx.x;
    int b = t >> 10, hh = t & 1023;
    const float* p = h + ((size_t)b * L_) * H_ + hh;
    float acc = 0.f;
#pragma unroll 8
    for (int l = 0; l < L_; ++l) acc += p[(size_t)l * H_];
    s[t] = acc;
}

// ---------------- compaction + t2 bias init ----------------
__global__ __launch_bounds__(256) void k_compact(const int* __restrict__ mask,
                                                 const float* __restrict__ ba,
                                                 const float* __restrict__ bs,
                                                 int* __restrict__ ridx,
                                                 int* __restrict__ cnt1,
                                                 float* __restrict__ cnt0,
                                                 float* __restrict__ t2) {
    int b = blockIdx.x;
    __shared__ int sm[L_];
    for (int l = threadIdx.x; l < L_; l += 256) sm[l] = mask[b * L_ + l];
    for (int e = threadIdx.x; e < D_; e += 256) t2[b * D_ + e] = ba[e] + bs[e];
    __syncthreads();
    if (threadIdx.x == 0) {
        int* rb = ridx + b * L_;
        int c = 0;
        for (int l = 0; l < L_; ++l) if (sm[l]) rb[c++] = l;
        int n1 = c;
        int last = (c > 0) ? rb[c - 1] : 0;
        for (; c < L_; ++c) rb[c] = last;
        cnt1[b] = n1;
        cnt0[b] = (float)(L_ - n1);
    }
}

// ---------------- Wb = bf16(W_a) ----------------
__global__ __launch_bounds__(256) void k_cvtW(const float* __restrict__ Wa,
                                              unsigned short* __restrict__ Wb) {
    int t = blockIdx.x * 256 + threadIdx.x;
    float4 v = ((const float4*)Wa)[t];
    ((uint2*)Wb)[t] = make_uint2(pk(v.x, v.y), pk(v.z, v.w));
}

// ---------------- Abf[b,j,:] = bf16([hs | xx][b, ridx[b,j], :])  (compacted gather)
// pads to 256-row granularity so the 256-row GEMM tiles always stage defined data
__global__ __launch_bounds__(256) void k_prep(const float* __restrict__ hs, const float* __restrict__ xx,
                                              const int* __restrict__ ridx, const int* __restrict__ cnt1,
                                              unsigned short* __restrict__ Abf) {
    int j = blockIdx.x;
    int b = blockIdx.y;
    int n1 = cnt1[b];
    if (j >= ((n1 + 255) & ~255)) return;
    int l = ridx[b * L_ + j];
    int t = threadIdx.x;
    size_t rb = ((size_t)(b * L_ + l)) << 10;
    const float* src = (t < 128) ? (hs + rb + t * 8) : (xx + rb + (t - 128) * 8);
    float4 v0 = *(const float4*)src;
    float4 v1 = *(const float4*)(src + 4);
    *(uint4*)(Abf + (((size_t)(b * L_ + j)) << 11) + t * 8) =
        make_uint4(pk(v0.x, v0.y), pk(v0.z, v0.w), pk(v1.x, v1.y), pk(v1.z, v1.w));
}

// ---------------- t2 += s @ W_s^T  (split-K, atomic reduce) ----------------
__global__ __launch_bounds__(256) void k_t2(const float* __restrict__ s, const float* __restrict__ Ws,
                                            float* __restrict__ t2) {
    __shared__ float As[16][64];
    __shared__ float Bs[16][64];
    int n0 = blockIdx.x * 64;
    int ks0 = blockIdx.y * 256;
    int tid = threadIdx.x;
    int tx = tid & 15, ty = tid >> 4;
    int r = tid >> 2, q = tid & 3;
    float acc[4][4] = {};
    for (int k0 = ks0; k0 < ks0 + 256; k0 += 16) {
        float4 av = *(const float4*)(s + (size_t)r * H_ + k0 + q * 4);
        float4 bv = *(const float4*)(Ws + (size_t)(n0 + r) * H_ + k0 + q * 4);
        __syncthreads();
        As[q*4+0][r] = av.x; As[q*4+1][r] = av.y; As[q*4+2][r] = av.z; As[q*4+3][r] = av.w;
        Bs[q*4+0][r] = bv.x; Bs[q*4+1][r] = bv.y; Bs[q*4+2][r] = bv.z; Bs[q*4+3][r] = bv.w;
        __syncthreads();
#pragma unroll
        for (int kk = 0; kk < 16; ++kk) {
            float a_[4], b_[4];
            *(float4*)&a_[0] = *(const float4*)&As[kk][ty * 4];
            *(float4*)&b_[0] = *(const float4*)&Bs[kk][tx * 4];
#pragma unroll
            for (int i = 0; i < 4; ++i)
#pragma unroll
                for (int j = 0; j < 4; ++j) acc[i][j] += a_[i] * b_[j];
        }
    }
#pragma unroll
    for (int i = 0; i < 4; ++i)
#pragma unroll
        for (int j = 0; j < 4; ++j)
            atomicAdd(&t2[(size_t)(ty * 4 + i) * D_ + n0 + tx * 4 + j], acc[i][j]);
}

// =====================================================================
// v4 MFMA GEMM: 256x256 tile, BK=64, 8 waves (2Mx4N), double-buffered LDS,
// 4 phases/K-tile, counted vmcnt(6), raw s_barrier + s_setprio (8-phase
// template, m201) + BANK-CONFLICT-FREE LDS permutation:
//   each STAGE writes one 1024B block (16 rows x 4 chunks of 16B);
//   cell (row r, chunk g) stored at position g*16 + r  (chunk-major).
//   Staging: linear LDS dest (HW requirement), permuted GLOBAL source
//   (lane j loads row w*16+(j&15), chunk j>>4).           [rule #21]
//   Fragment read lane (cl,g): byte g*256 + cl*16 -> bank-quad cl*4 mod 32,
//   distinct for every consecutive 8-lane group => conflict-free ds_read_b128.
// =====================================================================
#define BAR3() do { asm volatile("" ::: "memory"); __builtin_amdgcn_s_barrier(); asm volatile("" ::: "memory"); } while (0)

__global__ __launch_bounds__(512, 2) void k_gemm3(
    const unsigned short* __restrict__ Abf, const unsigned short* __restrict__ Wb,
    const float* __restrict__ t2, const int* __restrict__ cnt1,
    float* __restrict__ rowsum, unsigned short* __restrict__ P)
{
    __shared__ unsigned short lds[65536];   // 128 KB: buf u at u*32768 elems, A | B halves of 16384 elems

    int tid = threadIdx.x;
    int lane = tid & 63;
    int w = tid >> 6;          // 0..7
    int wm = w >> 2;           // 0..1  (M half of tile)
    int wn = w & 3;            // 0..3  (N quarter of tile)
    int g = lane >> 4;         // 0..3  (k-group within fragment)
    int cl = lane & 15;

    int n0 = blockIdx.x * 256;
    int jt = blockIdx.y;
    int b = jt >> 1;
    int j0 = (jt & 1) * 256;
    int n1 = cnt1[b];
    if (j0 >= n1) return;

    // ---- staging source (permuted): lane j of wave w -> row w*16+(j&15), 16B chunk j>>4 ----
    int sr = w * 16 + (lane & 15);
    int sce = ((lane >> 4) & 3) * 8;
    const unsigned short* aS0 = Abf + (((size_t)(b * L_ + j0 + sr)) << 11) + sce;
    const unsigned short* aS1 = aS0 + ((size_t)128 << 11);
    const unsigned short* bS0 = Wb + (((size_t)(n0 + sr)) << 11) + sce;
    const unsigned short* bS1 = bS0 + ((size_t)128 << 11);
    int wq = w * 512;          // wave-uniform LDS dest base (elements); HW adds lane*16B

#define STAGE_A3(h, tk, u) do { \
        const unsigned short* s_ = ((h) ? aS1 : aS0) + (tk) * 64; \
        unsigned short* d_ = &lds[(u) * 32768 + (h) * 8192 + wq]; \
        gload_lds16(s_, d_); gload_lds16(s_ + 32, d_ + 4096); } while (0)
#define STAGE_B3(h, tk, u) do { \
        const unsigned short* s_ = ((h) ? bS1 : bS0) + (tk) * 64; \
        unsigned short* d_ = &lds[(u) * 32768 + 16384 + (h) * 8192 + wq]; \
        gload_lds16(s_, d_); gload_lds16(s_ + 32, d_ + 4096); } while (0)

    // ---- fragment read offsets (elements, chunk-major blocks): block m at m*512,
    //      within block: g*128 + cl*8; khalf at +4096; buffer at +u*32768 ----
    int rdA = wm * 8192 + g * 128 + cl * 8;
    int rdB = 16384 + (wn >> 1) * 8192 + (wn & 1) * 2048 + g * 128 + cl * 8;

    f32x4 acc[8][4] = {};
    short8 af[4][2], bf0[2][2], bf1[2][2];

    // prologue: tile0 fully + 3 half-tiles of tile1 (A1(1) comes at t0/p0)
    STAGE_A3(0, 0, 0); STAGE_B3(0, 0, 0); STAGE_B3(1, 0, 0); STAGE_A3(1, 0, 0);
    STAGE_B3(0, 1, 1); STAGE_B3(1, 1, 1); STAGE_A3(0, 1, 1);
    asm volatile("s_waitcnt vmcnt(6)" ::: "memory");   // tile0 landed; 3 half-tiles in flight
    BAR3();

    for (int t = 0; t < 32; ++t) {
        int u = t & 1;
        int ub = u * 32768;
        int tn = (t + 1) & 31, tnn = (t + 2) & 31;   // tail wraps: stages dead-but-safe data

        // ===== phase 0: quadrant mf0-3 x nf0-1 =====
#pragma unroll
        for (int m = 0; m < 4; ++m) {
            af[m][0] = *(const short8*)&lds[ub + rdA + m * 512];
            af[m][1] = *(const short8*)&lds[ub + rdA + 4096 + m * 512];
        }
#pragma unroll
        for (int n = 0; n < 2; ++n) {
            bf0[n][0] = *(const short8*)&lds[ub + rdB + n * 512];
            bf0[n][1] = *(const short8*)&lds[ub + rdB + 4096 + n * 512];
        }
        STAGE_A3(1, tn, u ^ 1);                      // A1(t+1); A1 of that buf last read at (t-1)p2
        BAR3();
        __builtin_amdgcn_s_setprio(1);
#pragma unroll
        for (int m = 0; m < 4; ++m)
#pragma unroll
            for (int n = 0; n < 2; ++n) {
                acc[m][n] = __builtin_amdgcn_mfma_f32_16x16x32_bf16(af[m][0], bf0[n][0], acc[m][n], 0, 0, 0);
                acc[m][n] = __builtin_amdgcn_mfma_f32_16x16x32_bf16(af[m][1], bf0[n][1], acc[m][n], 0, 0, 0);
            }
        __builtin_amdgcn_s_setprio(0);
        BAR3();

        // ===== phase 1: quadrant mf0-3 x nf2-3 =====
#pragma unroll
        for (int n = 0; n < 2; ++n) {
            bf1[n][0] = *(const short8*)&lds[ub + rdB + (n + 2) * 512];
            bf1[n][1] = *(const short8*)&lds[ub + rdB + 4096 + (n + 2) * 512];
        }
        BAR3();
        __builtin_amdgcn_s_setprio(1);
#pragma unroll
        for (int m = 0; m < 4; ++m)
#pragma unroll
            for (int n = 0; n < 2; ++n) {
                acc[m][n + 2] = __builtin_amdgcn_mfma_f32_16x16x32_bf16(af[m][0], bf1[n][0], acc[m][n + 2], 0, 0, 0);
                acc[m][n + 2] = __builtin_amdgcn_mfma_f32_16x16x32_bf16(af[m][1], bf1[n][1], acc[m][n + 2], 0, 0, 0);
            }
        __builtin_amdgcn_s_setprio(0);
        BAR3();

        // ===== phase 2: quadrant mf4-7 x nf2-3 =====
#pragma unroll
        for (int m = 0; m < 4; ++m) {
            af[m][0] = *(const short8*)&lds[ub + rdA + (m + 4) * 512];
            af[m][1] = *(const short8*)&lds[ub + rdA + 4096 + (m + 4) * 512];
        }
        STAGE_B3(0, tnn, u);                         // B0(t+2); B0 of buf u read-free after p1
        BAR3();
        __builtin_amdgcn_s_setprio(1);
#pragma unroll
        for (int m = 0; m < 4; ++m)
#pragma unroll
            for (int n = 0; n < 2; ++n) {
                acc[m + 4][n + 2] = __builtin_amdgcn_mfma_f32_16x16x32_bf16(af[m][0], bf1[n][0], acc[m + 4][n + 2], 0, 0, 0);
                acc[m + 4][n + 2] = __builtin_amdgcn_mfma_f32_16x16x32_bf16(af[m][1], bf1[n][1], acc[m + 4][n + 2], 0, 0, 0);
            }
        __builtin_amdgcn_s_setprio(0);
        BAR3();

        // ===== phase 3: quadrant mf4-7 x nf0-1 =====
        STAGE_B3(1, tnn, u);                         // B1(t+2)
        STAGE_A3(0, tnn, u);                         // A0(t+2); A0 of buf u read-free after p2
        asm volatile("s_waitcnt vmcnt(6)" ::: "memory");  // retires all 4 half-tiles of tile t+1
        BAR3();
        __builtin_amdgcn_s_setprio(1);
#pragma unroll
        for (int m = 0; m < 4; ++m)
#pragma unroll
            for (int n = 0; n < 2; ++n) {
                acc[m + 4][n] = __builtin_amdgcn_mfma_f32_16x16x32_bf16(af[m][0], bf0[n][0], acc[m + 4][n], 0, 0, 0);
                acc[m + 4][n] = __builtin_amdgcn_mfma_f32_16x16x32_bf16(af[m][1], bf0[n][1], acc[m + 4][n], 0, 0, 0);
            }
        __builtin_amdgcn_s_setprio(0);
        BAR3();
    }
#undef STAGE_A3
#undef STAGE_B3

    // ===== epilogue: p = exp(tanh(acc + t2)), store P bf16, rowsum reduce =====
    asm volatile("s_waitcnt vmcnt(0)" ::: "memory");
    __syncthreads();

    float t2v[4]; int ecol[4];
#pragma unroll
    for (int n = 0; n < 4; ++n) { ecol[n] = n0 + wn * 64 + n * 16 + cl; t2v[n] = t2[b * D_ + ecol[n]]; }
    int orow0 = b * L_ + j0 + wm * 128;
    int qd = g;

    float rs[8][4] = {};
#pragma unroll
    for (int m = 0; m < 8; ++m) {
        int lrowb = m * 16 + qd * 4;
#pragma unroll
        for (int n = 0; n < 4; ++n) {
#pragma unroll
            for (int gg = 0; gg < 4; ++gg) {
                float p = fast_pexp(acc[m][n][gg] + t2v[n]);
                rs[m][gg] += p;
                P[(size_t)(orow0 + lrowb + gg) * D_ + ecol[n]] = f2bf(p);
            }
        }
    }
#pragma unroll
    for (int m = 0; m < 8; ++m)
#pragma unroll
        for (int gg = 0; gg < 4; ++gg) {
            float v = rs[m][gg];
            v += __shfl_xor(v, 1); v += __shfl_xor(v, 2);
            v += __shfl_xor(v, 4); v += __shfl_xor(v, 8);
            rs[m][gg] = v;
        }
    float* red = (float*)lds;
    if (tid < 256) red[tid] = 0.f;
    __syncthreads();
    if (cl == 0) {
#pragma unroll
        for (int m = 0; m < 8; ++m)
#pragma unroll
            for (int gg = 0; gg < 4; ++gg)
                atomicAdd(&red[wm * 128 + m * 16 + qd * 4 + gg], rs[m][gg]);
    }
    __syncthreads();
    if (tid < 256) atomicAdd(&rowsum[b * L_ + j0 + tid], red[tid]);
}

// ---------------- v2 finale: out[b,e] = (sum_j P/rowsum + cnt0/2048) * trig_a ----------------
__global__ __launch_bounds__(256) void k_fin2(const unsigned short* __restrict__ P,
                                              const float* __restrict__ rowsum,
                                              const int* __restrict__ cnt1,
                                              const int* __restrict__ trigger,
                                              const float* __restrict__ hs,
                                              const float* __restrict__ xx,
                                              float* __restrict__ out) {
    int b = blockIdx.y;
    __shared__ float iv[L_];
    int n1 = cnt1[b];
    int lceil = (n1 + 127) & ~127;
    for (int j = threadIdx.x; j < L_; j += 256)
        iv[j] = (j < n1) ? 1.f / rowsum[b * L_ + j] : 0.f;
    __syncthreads();
    int e0 = blockIdx.x * 512 + threadIdx.x * 2;
    const unsigned short* Pb = P + (((size_t)b) << 20) + e0;
    float s0 = 0.f, s1 = 0.f;
#pragma unroll 8
    for (int l = 0; l < lceil; ++l) {
        float f = iv[l];
        u32 pv = *(const u32*)(Pb + (((size_t)l) << 11));
        s0 += f * bf2f(pv & 0xffffu);
        s1 += f * bf2f(pv >> 16);
    }
    float base = (float)(L_ - n1) * (1.f / 2048.f);
    int trig = trigger[b];
    size_t tb = ((size_t)(b * L_ + trig)) << 10;
    float ta0 = (e0 < 1024) ? hs[tb + e0] : xx[tb + e0 - 1024];
    float ta1 = (e0 + 1 < 1024) ? hs[tb + e0 + 1] : xx[tb + e0 + 1 - 1024];
    out[b * D_ + e0]     = (s0 + base) * ta0;
    out[b * D_ + e0 + 1] = (s1 + base) * ta1;
}

// ================= v1 fallback kernels (round-4, proven) =================
#define BM 128
#define BN 128
#define BK 32
#define LDK 40
__global__ __launch_bounds__(256) void k_gemm(
    const float* __restrict__ hs, const float* __restrict__ xx,
    const float* __restrict__ Wa, const unsigned short* __restrict__ Wb,
    const float* __restrict__ t2,
    const int* __restrict__ ridx, const int* __restrict__ cnt1,
    float* __restrict__ rowsum,
    unsigned short* __restrict__ P, float* __restrict__ out, int mode)
{
    __shared__ unsigned short Asl[BM][LDK];
    __shared__ unsigned short Bsl[BN][BK];
    __shared__ float red[BM];

    int tid = threadIdx.x;
    int lane = tid & 63;
    int w = tid >> 6;
    int wm = w & 1, wn = w >> 1;

    int n0 = blockIdx.x * BN;
    int jt = blockIdx.y;
    int b = jt >> 2;
    int j0 = (jt & 3) * BM;
    int n1 = cnt1[b];
    if (j0 >= n1) return;

    int r = tid >> 1;
    int koff = (tid & 1) * 16;
    int l = ridx[b * L_ + j0 + r];
    size_t abase = ((size_t)b * L_ + l) * (size_t)H_;
    const float* hrow = hs + abase;
    const float* xrow = xx + abase;
    const float* browf = Wa + (size_t)(n0 + r) * D_;
    const unsigned short* bw0 = Wb ? Wb + (size_t)(n0 + (tid >> 2)) * D_ + (tid & 3) * 8 : nullptr;
    const unsigned short* bw1 = Wb ? Wb + (size_t)(n0 + 64 + (tid >> 2)) * D_ + (tid & 3) * 8 : nullptr;
    unsigned short* bs0 = &Bsl[0][0] + (size_t)tid * 8;
    unsigned short* bs1 = &Bsl[0][0] + (size_t)(tid + 256) * 8;
    bool useWb = (Wb != nullptr);

    f32x4 acc[4][4] = {};

    for (int k0 = 0; k0 < D_; k0 += BK) {
        int k = k0 + koff;
        const float* ap = (k < H_) ? (hrow + k) : (xrow + (k - H_));
        float4 a0 = *(const float4*)(ap);
        float4 a1 = *(const float4*)(ap + 4);
        float4 a2 = *(const float4*)(ap + 8);
        float4 a3 = *(const float4*)(ap + 12);
        uint4 bv0, bv1;
        float4 c0, c1, c2, c3;
        if (useWb) {
            bv0 = *(const uint4*)(bw0 + k0);
            bv1 = *(const uint4*)(bw1 + k0);
        } else {
            const float* bp = browf + k;
            c0 = *(const float4*)(bp);
            c1 = *(const float4*)(bp + 4);
            c2 = *(const float4*)(bp + 8);
            c3 = *(const float4*)(bp + 12);
        }
        __syncthreads();
        *(uint4*)&Asl[r][koff]     = make_uint4(pk(a0.x,a0.y), pk(a0.z,a0.w), pk(a1.x,a1.y), pk(a1.z,a1.w));
        *(uint4*)&Asl[r][koff + 8] = make_uint4(pk(a2.x,a2.y), pk(a2.z,a2.w), pk(a3.x,a3.y), pk(a3.z,a3.w));
        if (useWb) {
            *(uint4*)bs0 = bv0;
            *(uint4*)bs1 = bv1;
        } else {
            *(uint4*)&Bsl[r][koff]     = make_uint4(pk(c0.x,c0.y), pk(c0.z,c0.w), pk(c1.x,c1.y), pk(c1.z,c1.w));
            *(uint4*)&Bsl[r][koff + 8] = make_uint4(pk(c2.x,c2.y), pk(c2.z,c2.w), pk(c3.x,c3.y), pk(c3.z,c3.w));
        }
        __syncthreads();
        int kb = (lane >> 4) * 8;
        short8 af[4], bfg[4];
#pragma unroll
        for (int i = 0; i < 4; ++i) af[i]  = *(const short8*)&Asl[wm*64 + i*16 + (lane & 15)][kb];
#pragma unroll
        for (int j = 0; j < 4; ++j) bfg[j] = *(const short8*)&Bsl[wn*64 + j*16 + (lane & 15)][kb];
#pragma unroll
        for (int i = 0; i < 4; ++i)
#pragma unroll
            for (int j = 0; j < 4; ++j)
                acc[i][j] = __builtin_amdgcn_mfma_f32_16x16x32_bf16(af[i], bfg[j], acc[i][j], 0, 0, 0);
    }

    int cl = lane & 15, qd = lane >> 4;
    float t2v[4]; int ecol[4];
#pragma unroll
    for (int j = 0; j < 4; ++j) { ecol[j] = n0 + wn*64 + j*16 + cl; t2v[j] = t2[b * D_ + ecol[j]]; }
    int orow0 = b * L_ + j0;

    if (mode <= 1) {
        float rs[4][4] = {};
#pragma unroll
        for (int i = 0; i < 4; ++i) {
            int lrowb = wm*64 + i*16 + qd*4;
#pragma unroll
            for (int j = 0; j < 4; ++j) {
#pragma unroll
                for (int g = 0; g < 4; ++g) {
                    float p = fast_pexp(acc[i][j][g] + t2v[j]);
                    rs[i][g] += p;
                    if (mode == 0)
                        P[(size_t)(orow0 + lrowb + g) * D_ + ecol[j]] = f2bf(p);
                }
            }
        }
#pragma unroll
        for (int i = 0; i < 4; ++i)
#pragma unroll
            for (int g = 0; g < 4; ++g) {
                float v = rs[i][g];
                v += __shfl_xor(v, 1); v += __shfl_xor(v, 2);
                v += __shfl_xor(v, 4); v += __shfl_xor(v, 8);
                rs[i][g] = v;
            }
        __syncthreads();
        if (tid < BM) red[tid] = 0.f;
        __syncthreads();
        if (cl == 0) {
#pragma unroll
            for (int i = 0; i < 4; ++i)
#pragma unroll
                for (int g = 0; g < 4; ++g)
                    atomicAdd(&red[wm*64 + i*16 + qd*4 + g], rs[i][g]);
        }
        __syncthreads();
        if (tid < BM) atomicAdd(&rowsum[orow0 + tid], red[tid]);
    } else {
        float inv[4][4];
#pragma unroll
        for (int i = 0; i < 4; ++i)
#pragma unroll
            for (int g = 0; g < 4; ++g) {
                int lrow = wm*64 + i*16 + qd*4 + g;
                inv[i][g] = (j0 + lrow < n1) ? (1.f / rowsum[orow0 + lrow]) : 0.f;
            }
        float cs[4] = {};
#pragma unroll
        for (int i = 0; i < 4; ++i)
#pragma unroll
            for (int j = 0; j < 4; ++j)
#pragma unroll
                for (int g = 0; g < 4; ++g)
                    cs[j] += fast_pexp(acc[i][j][g] + t2v[j]) * inv[i][g];
#pragma unroll
        for (int j = 0; j < 4; ++j) {
            float v = cs[j];
            v += __shfl_xor(v, 16); v += __shfl_xor(v, 32);
            cs[j] = v;
        }
        __syncthreads();
        if (tid < BN) red[tid] = 0.f;
        __syncthreads();
        if (qd == 0) {
#pragma unroll
            for (int j = 0; j < 4; ++j) atomicAdd(&red[wn*64 + j*16 + cl], cs[j]);
        }
        __syncthreads();
        if (tid < BN) atomicAdd(&out[b * D_ + n0 + tid], red[tid]);
    }
}

__global__ __launch_bounds__(256) void k_inv(const int* __restrict__ cnt1,
                                             const float* __restrict__ rowsum,
                                             float* __restrict__ invr) {
    int t = blockIdx.x * 256 + threadIdx.x;
    int b = t >> 9, j = t & 511;
    invr[t] = (j < cnt1[b]) ? (1.f / rowsum[t]) : 0.f;
}

__global__ __launch_bounds__(256) void k_fin(const unsigned short* __restrict__ P,
                                             const float* __restrict__ invr,
                                             const int* __restrict__ cnt1,
                                             float* __restrict__ out) {
    int b = blockIdx.y;
    int lz = blockIdx.z * 128;
    if (lz >= cnt1[b]) return;
    int e0 = blockIdx.x * 512 + threadIdx.x * 2;
    const unsigned short* Pb = P + ((size_t)b * L_ + lz) * D_ + e0;
    const float* ivb = invr + b * L_ + lz;
    float s0 = 0.f, s1 = 0.f;
    for (int l = 0; l < 128; ++l) {
        float iv = ivb[l];
        u32 pv = *(const u32*)(Pb + (size_t)l * D_);
        s0 += iv * bf2f(pv & 0xffffu);
        s1 += iv * bf2f(pv >> 16);
    }
    atomicAdd(&out[b * D_ + e0], s0);
    atomicAdd(&out[b * D_ + e0 + 1], s1);
}

__global__ __launch_bounds__(256) void k_final(
    const float* __restrict__ hs, const float* __restrict__ xx,
    const int* __restrict__ trigger, const float* __restrict__ cnt0,
    float* __restrict__ out) {
    int t = blockIdx.x * 256 + threadIdx.x;
    int b = t >> 11, e = t & 2047;
    int trig = trigger[b];
    size_t base = ((size_t)b * L_ + trig) * 1024;
    float ta = (e < 1024) ? hs[base + e] : xx[base + e - 1024];
    out[t] = (out[t] + cnt0[b] * (1.0f / 2048.0f)) * ta;
}

extern "C" void kernel_launch(void* const* d_in, const int* in_sizes, int n_in,
                              void* d_out, int out_size, void* d_ws, size_t ws_size,
                              hipStream_t stream) {
    const float* hs = (const float*)d_in[0];
    const float* xx = (const float*)d_in[1];
    const float* Wa = (const float*)d_in[2];
    const float* ba = (const float*)d_in[3];
    const float* Ws = (const float*)d_in[4];
    const float* bs = (const float*)d_in[5];
    const int*   trig = (const int*)d_in[6];
    const int*   mask = (const int*)d_in[7];
    float* out = (float*)d_out;

    float* wsf    = (float*)d_ws;
    float* s      = wsf;                 // 65536
    float* t2     = s + 65536;           // 131072
    float* cnt0   = t2 + 131072;         // 64
    float* rowsum = cnt0 + 64;           // 32768
    float* invr   = rowsum + 32768;      // 32768 (v1 only)
    int*   cnt1   = (int*)(invr + 32768);// 64
    int*   ridx   = cnt1 + 64;           // 32768
    unsigned short* P   = (unsigned short*)(ridx + 32768);   // 134,217,728 B @ 1,180,160
    unsigned short* Wb  = P + (size_t)B_ * L_ * D_;          //   8,388,608 B
    unsigned short* Abf = Wb + (size_t)D_ * D_;              // 134,217,728 B

    const size_t BASE_B   = 1180160ull;
    const size_t NEED_P   = BASE_B + 134217728ull;
    const size_t NEED_WB  = NEED_P + 8388608ull;
    const size_t NEED_ALL = NEED_WB + 134217728ull;          // ~278 MB
    bool haveP   = ws_size >= NEED_P;
    bool haveWb  = ws_size >= NEED_WB;
    bool haveAll = ws_size >= NEED_ALL;

    (void)hipMemsetAsync(rowsum, 0, (size_t)B_ * L_ * sizeof(float), stream);

    k_s      <<<256, 256, 0, stream>>>(hs, s);
    k_compact<<<B_, 256, 0, stream>>>(mask, ba, bs, ridx, cnt1, cnt0, t2);
    k_t2     <<<dim3(32, 4), 256, 0, stream>>>(s, Ws, t2);

    if (haveAll) {
        // v4: 256^2 8-phase MFMA GEMM, all-bf16, counted-vmcnt async staging,
        // conflict-free chunk-major LDS blocks
        k_cvtW <<<4096, 256, 0, stream>>>(Wa, Wb);
        k_prep <<<dim3(512, 64), 256, 0, stream>>>(hs, xx, ridx, cnt1, Abf);
        k_gemm3<<<dim3(8, 128), 512, 0, stream>>>(Abf, Wb, t2, cnt1, rowsum, P);
        k_fin2 <<<dim3(4, 64), 256, 0, stream>>>(P, rowsum, cnt1, trig, hs, xx, out);
    } else {
        dim3 grid(D_ / BN, (B_ * L_) / BM);   // 16 x 256 (blocks past cnt1 self-exit)
        const unsigned short* WbArg = haveWb ? Wb : nullptr;
        if (haveWb) k_cvtW<<<4096, 256, 0, stream>>>(Wa, Wb);
        (void)hipMemsetAsync(out, 0, (size_t)B_ * D_ * sizeof(float), stream);
        if (haveP) {
            k_gemm<<<grid, 256, 0, stream>>>(hs, xx, Wa, WbArg, t2, ridx, cnt1, rowsum, P, out, 0);
            k_inv <<<(B_ * L_) / 256, 256, 0, stream>>>(cnt1, rowsum, invr);
            k_fin <<<dim3(4, 64, 4), 256, 0, stream>>>(P, invr, cnt1, out);
        } else {
            k_gemm<<<grid, 256, 0, stream>>>(hs, xx, Wa, WbArg, t2, ridx, cnt1, rowsum, P, out, 1);
            k_gemm<<<grid, 256, 0, stream>>>(hs, xx, Wa, WbArg, t2, ridx, cnt1, rowsum, P, out, 2);
        }
        k_final<<<(B_ * D_) / 256, 256, 0, stream>>>(hs, xx, trig, cnt0, out);
    }
}

// Round 3
// 728.869 us; speedup vs baseline: 1.0008x; 1.0008x over previous
//
#include <hip/hip_runtime.h>
#include <cstdint>

#define B_ 64
#define L_ 512
#define H_ 1024
#define D_ 2048

typedef __attribute__((ext_vector_type(8))) short short8;
typedef __attribute__((ext_vector_type(4))) float f32x4;
typedef unsigned int u32;

static __device__ __forceinline__ float bf2f(u32 lo16) {
    u32 u = lo16 << 16;
    return __builtin_bit_cast(float, u);
}
static __device__ __forceinline__ unsigned short f2bf(float f) {
    u32 u = __builtin_bit_cast(u32, f);
    u += 0x7fffu + ((u >> 16) & 1u);
    return (unsigned short)(u >> 16);
}
static __device__ __forceinline__ u32 pk(float x, float y) {
    return (u32)f2bf(x) | ((u32)f2bf(y) << 16);
}
static __device__ __forceinline__ float fast_pexp(float u) {
    u = fminf(15.f, fmaxf(-15.f, u));
    float ex = __expf(2.f * u);
    float th = (ex - 1.f) / (ex + 1.f);
    return __expf(th);
}
// async global->LDS, 16B per lane; lds base must be wave-uniform (HW: base + lane*16)
static __device__ __forceinline__ void gload_lds16(const unsigned short* g, unsigned short* l) {
    __builtin_amdgcn_global_load_lds((const __attribute__((address_space(1))) u32*)g,
                                     (__attribute__((address_space(3))) u32*)l, 16, 0, 0);
}

// ---------------- s[b,h] = sum_l h_state[b,l,h] ----------------
__global__ __launch_bounds__(256) void k_s(const float* __restrict__ h, float* __restrict__ s) {
    int t = blockIdx.x * 256 + threadIdx.x;
    int b = t >> 10, hh = t & 1023;
    const float* p = h + ((size_t)b * L_) * H_ + hh;
    float acc = 0.f;
#pragma unroll 8
    for (int l = 0; l < L_; ++l) acc += p[(size_t)l * H_];
    s[t] = acc;
}

// ---------------- compaction + t2 bias init ----------------
__global__ __launch_bounds__(256) void k_compact(const int* __restrict__ mask,
                                                 const float* __restrict__ ba,
                                                 const float* __restrict__ bs,
                                                 int* __restrict__ ridx,
                                                 int* __restrict__ cnt1,
                                                 float* __restrict__ cnt0,
                                                 float* __restrict__ t2) {
    int b = blockIdx.x;
    __shared__ int sm[L_];
    for (int l = threadIdx.x; l < L_; l += 256) sm[l] = mask[b * L_ + l];
    for (int e = threadIdx.x; e < D_; e += 256) t2[b * D_ + e] = ba[e] + bs[e];
    __syncthreads();
    if (threadIdx.x == 0) {
        int* rb = ridx + b * L_;
        int c = 0;
        for (int l = 0; l < L_; ++l) if (sm[l]) rb[c++] = l;
        int n1 = c;
        int last = (c > 0) ? rb[c - 1] : 0;
        for (; c < L_; ++c) rb[c] = last;
        cnt1[b] = n1;
        cnt0[b] = (float)(L_ - n1);
    }
}

// ---------------- Wb = bf16(W_a) ----------------
__global__ __launch_bounds__(256) void k_cvtW(const float* __restrict__ Wa,
                                              unsigned short* __restrict__ Wb) {
    int t = blockIdx.x * 256 + threadIdx.x;
    float4 v = ((const float4*)Wa)[t];
    ((uint2*)Wb)[t] = make_uint2(pk(v.x, v.y), pk(v.z, v.w));
}

// ---------------- Abf[b,j,:] = bf16([hs | xx][b, ridx[b,j], :])  (compacted gather)
// pads to 256-row granularity so the 256-row GEMM tiles always stage defined data
__global__ __launch_bounds__(256) void k_prep(const float* __restrict__ hs, const float* __restrict__ xx,
                                              const int* __restrict__ ridx, const int* __restrict__ cnt1,
                                              unsigned short* __restrict__ Abf) {
    int j = blockIdx.x;
    int b = blockIdx.y;
    int n1 = cnt1[b];
    if (j >= ((n1 + 255) & ~255)) return;
    int l = ridx[b * L_ + j];
    int t = threadIdx.x;
    size_t rb = ((size_t)(b * L_ + l)) << 10;
    const float* src = (t < 128) ? (hs + rb + t * 8) : (xx + rb + (t - 128) * 8);
    float4 v0 = *(const float4*)src;
    float4 v1 = *(const float4*)(src + 4);
    *(uint4*)(Abf + (((size_t)(b * L_ + j)) << 11) + t * 8) =
        make_uint4(pk(v0.x, v0.y), pk(v0.z, v0.w), pk(v1.x, v1.y), pk(v1.z, v1.w));
}

// ---------------- t2 += s @ W_s^T  (split-K, atomic reduce) ----------------
__global__ __launch_bounds__(256) void k_t2(const float* __restrict__ s, const float* __restrict__ Ws,
                                            float* __restrict__ t2) {
    __shared__ float As[16][64];
    __shared__ float Bs[16][64];
    int n0 = blockIdx.x * 64;
    int ks0 = blockIdx.y * 256;
    int tid = threadIdx.x;
    int tx = tid & 15, ty = tid >> 4;
    int r = tid >> 2, q = tid & 3;
    float acc[4][4] = {};
    for (int k0 = ks0; k0 < ks0 + 256; k0 += 16) {
        float4 av = *(const float4*)(s + (size_t)r * H_ + k0 + q * 4);
        float4 bv = *(const float4*)(Ws + (size_t)(n0 + r) * H_ + k0 + q * 4);
        __syncthreads();
        As[q*4+0][r] = av.x; As[q*4+1][r] = av.y; As[q*4+2][r] = av.z; As[q*4+3][r] = av.w;
        Bs[q*4+0][r] = bv.x; Bs[q*4+1][r] = bv.y; Bs[q*4+2][r] = bv.z; Bs[q*4+3][r] = bv.w;
        __syncthreads();
#pragma unroll
        for (int kk = 0; kk < 16; ++kk) {
            float a_[4], b_[4];
            *(float4*)&a_[0] = *(const float4*)&As[kk][ty * 4];
            *(float4*)&b_[0] = *(const float4*)&Bs[kk][tx * 4];
#pragma unroll
            for (int i = 0; i < 4; ++i)
#pragma unroll
                for (int j = 0; j < 4; ++j) acc[i][j] += a_[i] * b_[j];
        }
    }
#pragma unroll
    for (int i = 0; i < 4; ++i)
#pragma unroll
        for (int j = 0; j < 4; ++j)
            atomicAdd(&t2[(size_t)(ty * 4 + i) * D_ + n0 + tx * 4 + j], acc[i][j]);
}

// =====================================================================
// v5 MFMA GEMM: 256x256 tile, BK=64, 8 waves (2Mx4N), double-buffered LDS,
// counted vmcnt(6), conflict-free chunk-major LDS blocks (v4), PLUS:
//  * 2 barriers per K-tile (was 8): all reads of buf u that mid-tile stages
//    will overwrite (af0, bf0, bf1) are issued BEFORE bar(a); A1-region is
//    never overwritten mid-tile so af1 reads sit mid-tile race-free.
//  * XCD-local grid: grid=(jt 128 fastest, n0 8); all 8 n0-blocks of a jt
//    have blockIdx ≡ bx (mod 8) -> same XCD -> A-tile fetched into ONE L2.
//    jt = ((bx&7)<<4)|(bx>>3) balances even/odd jt across XCDs.
// =====================================================================
#define BAR3() do { asm volatile("" ::: "memory"); __builtin_amdgcn_s_barrier(); asm volatile("" ::: "memory"); } while (0)

__global__ __launch_bounds__(512, 2) void k_gemm3(
    const unsigned short* __restrict__ Abf, const unsigned short* __restrict__ Wb,
    const float* __restrict__ t2, const int* __restrict__ cnt1,
    float* __restrict__ rowsum, unsigned short* __restrict__ P)
{
    __shared__ unsigned short lds[65536];   // 128 KB: buf u at u*32768 elems, A | B halves of 16384 elems

    int tid = threadIdx.x;
    int lane = tid & 63;
    int w = tid >> 6;          // 0..7
    int wm = w >> 2;           // 0..1  (M half of tile)
    int wn = w & 3;            // 0..3  (N quarter of tile)
    int g = lane >> 4;         // 0..3  (k-group within fragment)
    int cl = lane & 15;

    int bx = blockIdx.x;                         // 0..127
    int jt = ((bx & 7) << 4) | (bx >> 3);        // XCD-balanced bijection
    int n0 = blockIdx.y * 256;
    int b = jt >> 1;
    int j0 = (jt & 1) * 256;
    int n1 = cnt1[b];
    if (j0 >= n1) return;

    // ---- staging source (permuted): lane j of wave w -> row w*16+(j&15), 16B chunk j>>4 ----
    int sr = w * 16 + (lane & 15);
    int sce = ((lane >> 4) & 3) * 8;
    const unsigned short* aS0 = Abf + (((size_t)(b * L_ + j0 + sr)) << 11) + sce;
    const unsigned short* aS1 = aS0 + ((size_t)128 << 11);
    const unsigned short* bS0 = Wb + (((size_t)(n0 + sr)) << 11) + sce;
    const unsigned short* bS1 = bS0 + ((size_t)128 << 11);
    int wq = w * 512;          // wave-uniform LDS dest base (elements); HW adds lane*16B

#define STAGE_A3(h, tk, u) do { \
        const unsigned short* s_ = ((h) ? aS1 : aS0) + (tk) * 64; \
        unsigned short* d_ = &lds[(u) * 32768 + (h) * 8192 + wq]; \
        gload_lds16(s_, d_); gload_lds16(s_ + 32, d_ + 4096); } while (0)
#define STAGE_B3(h, tk, u) do { \
        const unsigned short* s_ = ((h) ? bS1 : bS0) + (tk) * 64; \
        unsigned short* d_ = &lds[(u) * 32768 + 16384 + (h) * 8192 + wq]; \
        gload_lds16(s_, d_); gload_lds16(s_ + 32, d_ + 4096); } while (0)

    // ---- fragment read offsets (elements, chunk-major blocks): block m at m*512,
    //      within block: g*128 + cl*8; khalf at +4096; buffer at +u*32768 ----
    int rdA = wm * 8192 + g * 128 + cl * 8;
    int rdB = 16384 + (wn >> 1) * 8192 + (wn & 1) * 2048 + g * 128 + cl * 8;

    f32x4 acc[8][4] = {};
    short8 af[4][2], bf0[2][2], bf1[2][2];

    // prologue: tile0 fully + tile1 {B0,B1,A0}  (A1(1) staged at t=0)
    STAGE_A3(0, 0, 0); STAGE_B3(0, 0, 0); STAGE_B3(1, 0, 0); STAGE_A3(1, 0, 0);
    STAGE_B3(0, 1, 1); STAGE_B3(1, 1, 1); STAGE_A3(0, 1, 1);
    asm volatile("s_waitcnt vmcnt(6)" ::: "memory");   // tile0 landed; tile1's {B0,B1,A0} in flight
    BAR3();

    for (int t = 0; t < 32; ++t) {
        int u = t & 1;
        int ub = u * 32768;
        int tn = (t + 1) & 31, tnn = (t + 2) & 31;   // tail wraps: stages dead-but-safe data

        // ---- reads of regions that get overwritten mid-tile (A0, B0, B1 of buf u) ----
#pragma unroll
        for (int m = 0; m < 4; ++m) {
            af[m][0] = *(const short8*)&lds[ub + rdA + m * 512];
            af[m][1] = *(const short8*)&lds[ub + rdA + 4096 + m * 512];
        }
#pragma unroll
        for (int n = 0; n < 2; ++n) {
            bf0[n][0] = *(const short8*)&lds[ub + rdB + n * 512];
            bf0[n][1] = *(const short8*)&lds[ub + rdB + 4096 + n * 512];
        }
#pragma unroll
        for (int n = 0; n < 2; ++n) {
            bf1[n][0] = *(const short8*)&lds[ub + rdB + (n + 2) * 512];
            bf1[n][1] = *(const short8*)&lds[ub + rdB + 4096 + (n + 2) * 512];
        }
        STAGE_A3(1, tn, u ^ 1);        // A1(t+1); that region last read mid-tile t-1 (sep by bar b)
        BAR3();                        // bar (a): reads above done issuing before overwrites below

        // ===== Q0: mf0-3 x nf0-1, Q1: mf0-3 x nf2-3 =====
        __builtin_amdgcn_s_setprio(1);
#pragma unroll
        for (int h = 0; h < 2; ++h)
#pragma unroll
            for (int m = 0; m < 4; ++m)
#pragma unroll
                for (int n = 0; n < 2; ++n)
                    acc[m][n] = __builtin_amdgcn_mfma_f32_16x16x32_bf16(af[m][h], bf0[n][h], acc[m][n], 0, 0, 0);
#pragma unroll
        for (int h = 0; h < 2; ++h)
#pragma unroll
            for (int m = 0; m < 4; ++m)
#pragma unroll
                for (int n = 0; n < 2; ++n)
                    acc[m][n + 2] = __builtin_amdgcn_mfma_f32_16x16x32_bf16(af[m][h], bf1[n][h], acc[m][n + 2], 0, 0, 0);
        __builtin_amdgcn_s_setprio(0);

        // ---- overwrite staging for tile t+2 (regions read before bar a) ----
        STAGE_B3(0, tnn, u);
        STAGE_B3(1, tnn, u);
        STAGE_A3(0, tnn, u);

        // ---- A1 reads (region never overwritten mid-tile; WAR on af keeps them after Q1) ----
#pragma unroll
        for (int m = 0; m < 4; ++m) {
            af[m][0] = *(const short8*)&lds[ub + rdA + (m + 4) * 512];
            af[m][1] = *(const short8*)&lds[ub + rdA + 4096 + (m + 4) * 512];
        }

        // ===== Q2: mf4-7 x nf2-3, Q3: mf4-7 x nf0-1 =====
        __builtin_amdgcn_s_setprio(1);
#pragma unroll
        for (int h = 0; h < 2; ++h)
#pragma unroll
            for (int m = 0; m < 4; ++m)
#pragma unroll
                for (int n = 0; n < 2; ++n)
                    acc[m + 4][n + 2] = __builtin_amdgcn_mfma_f32_16x16x32_bf16(af[m][h], bf1[n][h], acc[m + 4][n + 2], 0, 0, 0);
#pragma unroll
        for (int h = 0; h < 2; ++h)
#pragma unroll
            for (int m = 0; m < 4; ++m)
#pragma unroll
                for (int n = 0; n < 2; ++n)
                    acc[m + 4][n] = __builtin_amdgcn_mfma_f32_16x16x32_bf16(af[m][h], bf0[n][h], acc[m + 4][n], 0, 0, 0);
        __builtin_amdgcn_s_setprio(0);

        asm volatile("s_waitcnt vmcnt(6)" ::: "memory");  // retires tile t+1's 4 half-tiles
        BAR3();                        // bar (b): globalize staging-complete
    }
#undef STAGE_A3
#undef STAGE_B3

    // ===== epilogue: p = exp(tanh(acc + t2)), store P bf16, rowsum reduce =====
    asm volatile("s_waitcnt vmcnt(0)" ::: "memory");
    __syncthreads();

    float t2v[4]; int ecol[4];
#pragma unroll
    for (int n = 0; n < 4; ++n) { ecol[n] = n0 + wn * 64 + n * 16 + cl; t2v[n] = t2[b * D_ + ecol[n]]; }
    int orow0 = b * L_ + j0 + wm * 128;
    int qd = g;

    float rs[8][4] = {};
#pragma unroll
    for (int m = 0; m < 8; ++m) {
        int lrowb = m * 16 + qd * 4;
#pragma unroll
        for (int n = 0; n < 4; ++n) {
#pragma unroll
            for (int gg = 0; gg < 4; ++gg) {
                float p = fast_pexp(acc[m][n][gg] + t2v[n]);
                rs[m][gg] += p;
                P[(size_t)(orow0 + lrowb + gg) * D_ + ecol[n]] = f2bf(p);
            }
        }
    }
#pragma unroll
    for (int m = 0; m < 8; ++m)
#pragma unroll
        for (int gg = 0; gg < 4; ++gg) {
            float v = rs[m][gg];
            v += __shfl_xor(v, 1); v += __shfl_xor(v, 2);
            v += __shfl_xor(v, 4); v += __shfl_xor(v, 8);
            rs[m][gg] = v;
        }
    float* red = (float*)lds;
    if (tid < 256) red[tid] = 0.f;
    __syncthreads();
    if (cl == 0) {
#pragma unroll
        for (int m = 0; m < 8; ++m)
#pragma unroll
            for (int gg = 0; gg < 4; ++gg)
                atomicAdd(&red[wm * 128 + m * 16 + qd * 4 + gg], rs[m][gg]);
    }
    __syncthreads();
    if (tid < 256) atomicAdd(&rowsum[b * L_ + j0 + tid], red[tid]);
}

// ---------------- v2 finale: out[b,e] = (sum_j P/rowsum + cnt0/2048) * trig_a ----------------
__global__ __launch_bounds__(256) void k_fin2(const unsigned short* __restrict__ P,
                                              const float* __restrict__ rowsum,
                                              const int* __restrict__ cnt1,
                                              const int* __restrict__ trigger,
                                              const float* __restrict__ hs,
                                              const float* __restrict__ xx,
                                              float* __restrict__ out) {
    int b = blockIdx.y;
    __shared__ float iv[L_];
    int n1 = cnt1[b];
    int lceil = (n1 + 127) & ~127;
    for (int j = threadIdx.x; j < L_; j += 256)
        iv[j] = (j < n1) ? 1.f / rowsum[b * L_ + j] : 0.f;
    __syncthreads();
    int e0 = blockIdx.x * 512 + threadIdx.x * 2;
    const unsigned short* Pb = P + (((size_t)b) << 20) + e0;
    float s0 = 0.f, s1 = 0.f;
#pragma unroll 8
    for (int l = 0; l < lceil; ++l) {
        float f = iv[l];
        u32 pv = *(const u32*)(Pb + (((size_t)l) << 11));
        s0 += f * bf2f(pv & 0xffffu);
        s1 += f * bf2f(pv >> 16);
    }
    float base = (float)(L_ - n1) * (1.f / 2048.f);
    int trig = trigger[b];
    size_t tb = ((size_t)(b * L_ + trig)) << 10;
    float ta0 = (e0 < 1024) ? hs[tb + e0] : xx[tb + e0 - 1024];
    float ta1 = (e0 + 1 < 1024) ? hs[tb + e0 + 1] : xx[tb + e0 + 1 - 1024];
    out[b * D_ + e0]     = (s0 + base) * ta0;
    out[b * D_ + e0 + 1] = (s1 + base) * ta1;
}

// ================= v1 fallback kernels (round-4, proven) =================
#define BM 128
#define BN 128
#define BK 32
#define LDK 40
__global__ __launch_bounds__(256) void k_gemm(
    const float* __restrict__ hs, const float* __restrict__ xx,
    const float* __restrict__ Wa, const unsigned short* __restrict__ Wb,
    const float* __restrict__ t2,
    const int* __restrict__ ridx, const int* __restrict__ cnt1,
    float* __restrict__ rowsum,
    unsigned short* __restrict__ P, float* __restrict__ out, int mode)
{
    __shared__ unsigned short Asl[BM][LDK];
    __shared__ unsigned short Bsl[BN][BK];
    __shared__ float red[BM];

    int tid = threadIdx.x;
    int lane = tid & 63;
    int w = tid >> 6;
    int wm = w & 1, wn = w >> 1;

    int n0 = blockIdx.x * BN;
    int jt = blockIdx.y;
    int b = jt >> 2;
    int j0 = (jt & 3) * BM;
    int n1 = cnt1[b];
    if (j0 >= n1) return;

    int r = tid >> 1;
    int koff = (tid & 1) * 16;
    int l = ridx[b * L_ + j0 + r];
    size_t abase = ((size_t)b * L_ + l) * (size_t)H_;
    const float* hrow = hs + abase;
    const float* xrow = xx + abase;
    const float* browf = Wa + (size_t)(n0 + r) * D_;
    const unsigned short* bw0 = Wb ? Wb + (size_t)(n0 + (tid >> 2)) * D_ + (tid & 3) * 8 : nullptr;
    const unsigned short* bw1 = Wb ? Wb + (size_t)(n0 + 64 + (tid >> 2)) * D_ + (tid & 3) * 8 : nullptr;
    unsigned short* bs0 = &Bsl[0][0] + (size_t)tid * 8;
    unsigned short* bs1 = &Bsl[0][0] + (size_t)(tid + 256) * 8;
    bool useWb = (Wb != nullptr);

    f32x4 acc[4][4] = {};

    for (int k0 = 0; k0 < D_; k0 += BK) {
        int k = k0 + koff;
        const float* ap = (k < H_) ? (hrow + k) : (xrow + (k - H_));
        float4 a0 = *(const float4*)(ap);
        float4 a1 = *(const float4*)(ap + 4);
        float4 a2 = *(const float4*)(ap + 8);
        float4 a3 = *(const float4*)(ap + 12);
        uint4 bv0, bv1;
        float4 c0, c1, c2, c3;
        if (useWb) {
            bv0 = *(const uint4*)(bw0 + k0);
            bv1 = *(const uint4*)(bw1 + k0);
        } else {
            const float* bp = browf + k;
            c0 = *(const float4*)(bp);
            c1 = *(const float4*)(bp + 4);
            c2 = *(const float4*)(bp + 8);
            c3 = *(const float4*)(bp + 12);
        }
        __syncthreads();
        *(uint4*)&Asl[r][koff]     = make_uint4(pk(a0.x,a0.y), pk(a0.z,a0.w), pk(a1.x,a1.y), pk(a1.z,a1.w));
        *(uint4*)&Asl[r][koff + 8] = make_uint4(pk(a2.x,a2.y), pk(a2.z,a2.w), pk(a3.x,a3.y), pk(a3.z,a3.w));
        if (useWb) {
            *(uint4*)bs0 = bv0;
            *(uint4*)bs1 = bv1;
        } else {
            *(uint4*)&Bsl[r][koff]     = make_uint4(pk(c0.x,c0.y), pk(c0.z,c0.w), pk(c1.x,c1.y), pk(c1.z,c1.w));
            *(uint4*)&Bsl[r][koff + 8] = make_uint4(pk(c2.x,c2.y), pk(c2.z,c2.w), pk(c3.x,c3.y), pk(c3.z,c3.w));
        }
        __syncthreads();
        int kb = (lane >> 4) * 8;
        short8 af[4], bfg[4];
#pragma unroll
        for (int i = 0; i < 4; ++i) af[i]  = *(const short8*)&Asl[wm*64 + i*16 + (lane & 15)][kb];
#pragma unroll
        for (int j = 0; j < 4; ++j) bfg[j] = *(const short8*)&Bsl[wn*64 + j*16 + (lane & 15)][kb];
#pragma unroll
        for (int i = 0; i < 4; ++i)
#pragma unroll
            for (int j = 0; j < 4; ++j)
                acc[i][j] = __builtin_amdgcn_mfma_f32_16x16x32_bf16(af[i], bfg[j], acc[i][j], 0, 0, 0);
    }

    int cl = lane & 15, qd = lane >> 4;
    float t2v[4]; int ecol[4];
#pragma unroll
    for (int j = 0; j < 4; ++j) { ecol[j] = n0 + wn*64 + j*16 + cl; t2v[j] = t2[b * D_ + ecol[j]]; }
    int orow0 = b * L_ + j0;

    if (mode <= 1) {
        float rs[4][4] = {};
#pragma unroll
        for (int i = 0; i < 4; ++i) {
            int lrowb = wm*64 + i*16 + qd*4;
#pragma unroll
            for (int j = 0; j < 4; ++j) {
#pragma unroll
                for (int g = 0; g < 4; ++g) {
                    float p = fast_pexp(acc[i][j][g] + t2v[j]);
                    rs[i][g] += p;
                    if (mode == 0)
                        P[(size_t)(orow0 + lrowb + g) * D_ + ecol[j]] = f2bf(p);
                }
            }
        }
#pragma unroll
        for (int i = 0; i < 4; ++i)
#pragma unroll
            for (int g = 0; g < 4; ++g) {
                float v = rs[i][g];
                v += __shfl_xor(v, 1); v += __shfl_xor(v, 2);
                v += __shfl_xor(v, 4); v += __shfl_xor(v, 8);
                rs[i][g] = v;
            }
        __syncthreads();
        if (tid < BM) red[tid] = 0.f;
        __syncthreads();
        if (cl == 0) {
#pragma unroll
            for (int i = 0; i < 4; ++i)
#pragma unroll
                for (int g = 0; g < 4; ++g)
                    atomicAdd(&red[wm*64 + i*16 + qd*4 + g], rs[i][g]);
        }
        __syncthreads();
        if (tid < BM) atomicAdd(&rowsum[orow0 + tid], red[tid]);
    } else {
        float inv[4][4];
#pragma unroll
        for (int i = 0; i < 4; ++i)
#pragma unroll
            for (int g = 0; g < 4; ++g) {
                int lrow = wm*64 + i*16 + qd*4 + g;
                inv[i][g] = (j0 + lrow < n1) ? (1.f / rowsum[orow0 + lrow]) : 0.f;
            }
        float cs[4] = {};
#pragma unroll
        for (int i = 0; i < 4; ++i)
#pragma unroll
            for (int j = 0; j < 4; ++j)
#pragma unroll
                for (int g = 0; g < 4; ++g)
                    cs[j] += fast_pexp(acc[i][j][g] + t2v[j]) * inv[i][g];
#pragma unroll
        for (int j = 0; j < 4; ++j) {
            float v = cs[j];
            v += __shfl_xor(v, 16); v += __shfl_xor(v, 32);
            cs[j] = v;
        }
        __syncthreads();
        if (tid < BN) red[tid] = 0.f;
        __syncthreads();
        if (qd == 0) {
#pragma unroll
            for (int j = 0; j < 4; ++j) atomicAdd(&red[wn*64 + j*16 + cl], cs[j]);
        }
        __syncthreads();
        if (tid < BN) atomicAdd(&out[b * D_ + n0 + tid], red[tid]);
    }
}

__global__ __launch_bounds__(256) void k_inv(const int* __restrict__ cnt1,
                                             const float* __restrict__ rowsum,
                                             float* __restrict__ invr) {
    int t = blockIdx.x * 256 + threadIdx.x;
    int b = t >> 9, j = t & 511;
    invr[t] = (j < cnt1[b]) ? (1.f / rowsum[t]) : 0.f;
}

__global__ __launch_bounds__(256) void k_fin(const unsigned short* __restrict__ P,
                                             const float* __restrict__ invr,
                                             const int* __restrict__ cnt1,
                                             float* __restrict__ out) {
    int b = blockIdx.y;
    int lz = blockIdx.z * 128;
    if (lz >= cnt1[b]) return;
    int e0 = blockIdx.x * 512 + threadIdx.x * 2;
    const unsigned short* Pb = P + ((size_t)b * L_ + lz) * D_ + e0;
    const float* ivb = invr + b * L_ + lz;
    float s0 = 0.f, s1 = 0.f;
    for (int l = 0; l < 128; ++l) {
        float iv = ivb[l];
        u32 pv = *(const u32*)(Pb + (size_t)l * D_);
        s0 += iv * bf2f(pv & 0xffffu);
        s1 += iv * bf2f(pv >> 16);
    }
    atomicAdd(&out[b * D_ + e0], s0);
    atomicAdd(&out[b * D_ + e0 + 1], s1);
}

__global__ __launch_bounds__(256) void k_final(
    const float* __restrict__ hs, const float* __restrict__ xx,
    const int* __restrict__ trigger, const float* __restrict__ cnt0,
    float* __restrict__ out) {
    int t = blockIdx.x * 256 + threadIdx.x;
    int b = t >> 11, e = t & 2047;
    int trig = trigger[b];
    size_t base = ((size_t)b * L_ + trig) * 1024;
    float ta = (e < 1024) ? hs[base + e] : xx[base + e - 1024];
    out[t] = (out[t] + cnt0[b] * (1.0f / 2048.0f)) * ta;
}

extern "C" void kernel_launch(void* const* d_in, const int* in_sizes, int n_in,
                              void* d_out, int out_size, void* d_ws, size_t ws_size,
                              hipStream_t stream) {
    const float* hs = (const float*)d_in[0];
    const float* xx = (const float*)d_in[1];
    const float* Wa = (const float*)d_in[2];
    const float* ba = (const float*)d_in[3];
    const float* Ws = (const float*)d_in[4];
    const float* bs = (const float*)d_in[5];
    const int*   trig = (const int*)d_in[6];
    const int*   mask = (const int*)d_in[7];
    float* out = (float*)d_out;

    float* wsf    = (float*)d_ws;
    float* s      = wsf;                 // 65536
    float* t2     = s + 65536;           // 131072
    float* cnt0   = t2 + 131072;         // 64
    float* rowsum = cnt0 + 64;           // 32768
    float* invr   = rowsum + 32768;      // 32768 (v1 only)
    int*   cnt1   = (int*)(invr + 32768);// 64
    int*   ridx   = cnt1 + 64;           // 32768
    unsigned short* P   = (unsigned short*)(ridx + 32768);   // 134,217,728 B @ 1,180,160
    unsigned short* Wb  = P + (size_t)B_ * L_ * D_;          //   8,388,608 B
    unsigned short* Abf = Wb + (size_t)D_ * D_;              // 134,217,728 B

    const size_t BASE_B   = 1180160ull;
    const size_t NEED_P   = BASE_B + 134217728ull;
    const size_t NEED_WB  = NEED_P + 8388608ull;
    const size_t NEED_ALL = NEED_WB + 134217728ull;          // ~278 MB
    bool haveP   = ws_size >= NEED_P;
    bool haveWb  = ws_size >= NEED_WB;
    bool haveAll = ws_size >= NEED_ALL;

    (void)hipMemsetAsync(rowsum, 0, (size_t)B_ * L_ * sizeof(float), stream);

    k_s      <<<256, 256, 0, stream>>>(hs, s);
    k_compact<<<B_, 256, 0, stream>>>(mask, ba, bs, ridx, cnt1, cnt0, t2);
    k_t2     <<<dim3(32, 4), 256, 0, stream>>>(s, Ws, t2);

    if (haveAll) {
        // v5: 256^2 MFMA GEMM, 2-barrier K-tile, XCD-local grid, counted-vmcnt staging
        k_cvtW <<<4096, 256, 0, stream>>>(Wa, Wb);
        k_prep <<<dim3(512, 64), 256, 0, stream>>>(hs, xx, ridx, cnt1, Abf);
        k_gemm3<<<dim3(128, 8), 512, 0, stream>>>(Abf, Wb, t2, cnt1, rowsum, P);
        k_fin2 <<<dim3(4, 64), 256, 0, stream>>>(P, rowsum, cnt1, trig, hs, xx, out);
    } else {
        dim3 grid(D_ / BN, (B_ * L_) / BM);   // 16 x 256 (blocks past cnt1 self-exit)
        const unsigned short* WbArg = haveWb ? Wb : nullptr;
        if (haveWb) k_cvtW<<<4096, 256, 0, stream>>>(Wa, Wb);
        (void)hipMemsetAsync(out, 0, (size_t)B_ * D_ * sizeof(float), stream);
        if (haveP) {
            k_gemm<<<grid, 256, 0, stream>>>(hs, xx, Wa, WbArg, t2, ridx, cnt1, rowsum, P, out, 0);
            k_inv <<<(B_ * L_) / 256, 256, 0, stream>>>(cnt1, rowsum, invr);
            k_fin <<<dim3(4, 64, 4), 256, 0, stream>>>(P, invr, cnt1, out);
        } else {
            k_gemm<<<grid, 256, 0, stream>>>(hs, xx, Wa, WbArg, t2, ridx, cnt1, rowsum, P, out, 1);
            k_gemm<<<grid, 256, 0, stream>>>(hs, xx, Wa, WbArg, t2, ridx, cnt1, rowsum, P, out, 2);
        }
        k_final<<<(B_ * D_) / 256, 256, 0, stream>>>(hs, xx, trig, cnt0, out);
    }
}

// Round 4
// 675.292 us; speedup vs baseline: 1.0802x; 1.0793x over previous
//
#include <hip/hip_runtime.h>
#include <cstdint>

#define B_ 64
#define L_ 512
#define H_ 1024
#define D_ 2048

typedef __attribute__((ext_vector_type(8))) short short8;
typedef __attribute__((ext_vector_type(4))) float f32x4;
typedef unsigned int u32;

static __device__ __forceinline__ float bf2f(u32 lo16) {
    u32 u = lo16 << 16;
    return __builtin_bit_cast(float, u);
}
static __device__ __forceinline__ unsigned short f2bf(float f) {
    u32 u = __builtin_bit_cast(u32, f);
    u += 0x7fffu + ((u >> 16) & 1u);
    return (unsigned short)(u >> 16);
}
static __device__ __forceinline__ u32 pk(float x, float y) {
    return (u32)f2bf(x) | ((u32)f2bf(y) << 16);
}
static __device__ __forceinline__ float fast_pexp(float u) {
    u = fminf(15.f, fmaxf(-15.f, u));
    float ex = __expf(2.f * u);
    float th = (ex - 1.f) / (ex + 1.f);
    return __expf(th);
}
// async global->LDS, 16B per lane; lds base must be wave-uniform (HW: base + lane*16)
static __device__ __forceinline__ void gload_lds16(const unsigned short* g, unsigned short* l) {
    __builtin_amdgcn_global_load_lds((const __attribute__((address_space(1))) u32*)g,
                                     (__attribute__((address_space(3))) u32*)l, 16, 0, 0);
}

// ---------------- s[b,h] = sum_l h_state[b,l,h] ----------------
__global__ __launch_bounds__(256) void k_s(const float* __restrict__ h, float* __restrict__ s) {
    int t = blockIdx.x * 256 + threadIdx.x;
    int b = t >> 10, hh = t & 1023;
    const float* p = h + ((size_t)b * L_) * H_ + hh;
    float acc = 0.f;
#pragma unroll 8
    for (int l = 0; l < L_; ++l) acc += p[(size_t)l * H_];
    s[t] = acc;
}

// ---------------- compaction + t2 bias init ----------------
__global__ __launch_bounds__(256) void k_compact(const int* __restrict__ mask,
                                                 const float* __restrict__ ba,
                                                 const float* __restrict__ bs,
                                                 int* __restrict__ ridx,
                                                 int* __restrict__ cnt1,
                                                 float* __restrict__ cnt0,
                                                 float* __restrict__ t2) {
    int b = blockIdx.x;
    __shared__ int sm[L_];
    for (int l = threadIdx.x; l < L_; l += 256) sm[l] = mask[b * L_ + l];
    for (int e = threadIdx.x; e < D_; e += 256) t2[b * D_ + e] = ba[e] + bs[e];
    __syncthreads();
    if (threadIdx.x == 0) {
        int* rb = ridx + b * L_;
        int c = 0;
        for (int l = 0; l < L_; ++l) if (sm[l]) rb[c++] = l;
        int n1 = c;
        int last = (c > 0) ? rb[c - 1] : 0;
        for (; c < L_; ++c) rb[c] = last;
        cnt1[b] = n1;
        cnt0[b] = (float)(L_ - n1);
    }
}

// ---------------- Wb = bf16(W_a), GEMM-staging-tiled layout ----------------
// chunk c -> [p(8)][rh(2)][tk(32)][w(8)][kh(2)][g(4)][cl(16)] ; 8 elems per chunk.
// row = p*256+rh*128+w*16+cl ; k = tk*64+kh*32+g*8. Write coalesced; reads are
// 16 rows x 128B full lines per wave.
__global__ __launch_bounds__(256) void k_cvtW(const float* __restrict__ Wa,
                                              unsigned short* __restrict__ Wb) {
    int c = blockIdx.x * 256 + threadIdx.x;          // 0..524287
    int p  = c >> 16;
    int rh = (c >> 15) & 1;
    int tk = (c >> 10) & 31;
    int w  = (c >> 7) & 7;
    int kh = (c >> 6) & 1;
    int g  = (c >> 4) & 3;
    int cl = c & 15;
    int row = p * 256 + rh * 128 + w * 16 + cl;
    int k = tk * 64 + kh * 32 + g * 8;
    const float* src = Wa + (size_t)row * D_ + k;
    float4 v0 = *(const float4*)src;
    float4 v1 = *(const float4*)(src + 4);
    *(uint4*)(Wb + (size_t)c * 8) =
        make_uint4(pk(v0.x, v0.y), pk(v0.z, v0.w), pk(v1.x, v1.y), pk(v1.z, v1.w));
}

// ---------------- Abf: bf16 compacted gather in GEMM-staging-tiled layout ----------------
// per b: chunk c -> [rh(4)][tk(32)][w(8)][kh(2)][g(4)][cl(16)] ; j = rh*128+w*16+cl.
// pads to 256-row granularity so GEMM tiles always stage defined data.
__global__ __launch_bounds__(256) void k_prep(const float* __restrict__ hs, const float* __restrict__ xx,
                                              const int* __restrict__ ridx, const int* __restrict__ cnt1,
                                              unsigned short* __restrict__ Abf) {
    int b = blockIdx.y;
    int n1 = cnt1[b];
    int lceil = (n1 + 255) & ~255;
    int c = blockIdx.x * 256 + threadIdx.x;          // 0..131071 within b
    int rh = c >> 15;
    int tk = (c >> 10) & 31;
    int w  = (c >> 7) & 7;
    int kh = (c >> 6) & 1;
    int g  = (c >> 4) & 3;
    int cl = c & 15;
    int j = rh * 128 + w * 16 + cl;
    if (j >= lceil) return;
    int l = ridx[b * L_ + j];
    int k = tk * 64 + kh * 32 + g * 8;
    size_t rb = ((size_t)(b * L_ + l)) << 10;
    const float* src = (k < H_) ? (hs + rb + k) : (xx + rb + (k - H_));
    float4 v0 = *(const float4*)src;
    float4 v1 = *(const float4*)(src + 4);
    *(uint4*)(Abf + ((size_t)b << 20) + (size_t)c * 8) =
        make_uint4(pk(v0.x, v0.y), pk(v0.z, v0.w), pk(v1.x, v1.y), pk(v1.z, v1.w));
}

// ---------------- t2 += s @ W_s^T  (split-K, atomic reduce) ----------------
__global__ __launch_bounds__(256) void k_t2(const float* __restrict__ s, const float* __restrict__ Ws,
                                            float* __restrict__ t2) {
    __shared__ float As[16][64];
    __shared__ float Bs[16][64];
    int n0 = blockIdx.x * 64;
    int ks0 = blockIdx.y * 256;
    int tid = threadIdx.x;
    int tx = tid & 15, ty = tid >> 4;
    int r = tid >> 2, q = tid & 3;
    float acc[4][4] = {};
    for (int k0 = ks0; k0 < ks0 + 256; k0 += 16) {
        float4 av = *(const float4*)(s + (size_t)r * H_ + k0 + q * 4);
        float4 bv = *(const float4*)(Ws + (size_t)(n0 + r) * H_ + k0 + q * 4);
        __syncthreads();
        As[q*4+0][r] = av.x; As[q*4+1][r] = av.y; As[q*4+2][r] = av.z; As[q*4+3][r] = av.w;
        Bs[q*4+0][r] = bv.x; Bs[q*4+1][r] = bv.y; Bs[q*4+2][r] = bv.z; Bs[q*4+3][r] = bv.w;
        __syncthreads();
#pragma unroll
        for (int kk = 0; kk < 16; ++kk) {
            float a_[4], b_[4];
            *(float4*)&a_[0] = *(const float4*)&As[kk][ty * 4];
            *(float4*)&b_[0] = *(const float4*)&Bs[kk][tx * 4];
#pragma unroll
            for (int i = 0; i < 4; ++i)
#pragma unroll
                for (int j = 0; j < 4; ++j) acc[i][j] += a_[i] * b_[j];
        }
    }
#pragma unroll
    for (int i = 0; i < 4; ++i)
#pragma unroll
        for (int j = 0; j < 4; ++j)
            atomicAdd(&t2[(size_t)(ty * 4 + i) * D_ + n0 + tx * 4 + j], acc[i][j]);
}

// =====================================================================
// v6 MFMA GEMM: 256x256 tile, BK=64, 8 waves (2Mx4N), double-buffered LDS,
// counted vmcnt(6), 2 barriers/K-tile, XCD-local grid (v5), PLUS:
//  * CONTIGUOUS staging: Abf/Wb stored pre-tiled in the exact LDS order,
//    so each global_load_lds reads a linear 1KB block (8 full lines,
//    lane j at +j*16B) instead of 16 scattered 64B segments. LDS content
//    is byte-identical to v5 -> fragment reads & math unchanged.
// =====================================================================
#define BAR3() do { asm volatile("" ::: "memory"); __builtin_amdgcn_s_barrier(); asm volatile("" ::: "memory"); } while (0)

__global__ __launch_bounds__(512, 2) void k_gemm3(
    const unsigned short* __restrict__ Abf, const unsigned short* __restrict__ Wb,
    const float* __restrict__ t2, const int* __restrict__ cnt1,
    float* __restrict__ rowsum, unsigned short* __restrict__ P)
{
    __shared__ unsigned short lds[65536];   // 128 KB: buf u at u*32768 elems, A | B halves of 16384 elems

    int tid = threadIdx.x;
    int lane = tid & 63;
    int w = tid >> 6;          // 0..7
    int wm = w >> 2;           // 0..1  (M half of tile)
    int wn = w & 3;            // 0..3  (N quarter of tile)
    int g = lane >> 4;         // 0..3  (k-group within fragment)
    int cl = lane & 15;

    int bx = blockIdx.x;                         // 0..127
    int jt = ((bx & 7) << 4) | (bx >> 3);        // XCD-balanced bijection
    int n0 = blockIdx.y * 256;
    int b = jt >> 1;
    int j0 = (jt & 1) * 256;
    int n1 = cnt1[b];
    if (j0 >= n1) return;

    // ---- staging: contiguous 1KB per gload; lane j reads slab + j*16B ----
    const unsigned short* aT = Abf + ((size_t)b << 20) + (size_t)(j0 >> 7) * 262144;
    const unsigned short* bT = Wb + (size_t)blockIdx.y * 524288;
    int srcOff = w * 1024 + lane * 8;            // per-lane source offset (elems)
    int wq = w * 512;                            // wave-uniform LDS dest base (elems)

#define STAGE_A3(h, tk, u) do { \
        const unsigned short* s_ = aT + (h) * 262144 + (tk) * 8192 + srcOff; \
        unsigned short* d_ = &lds[(u) * 32768 + (h) * 8192 + wq]; \
        gload_lds16(s_, d_); gload_lds16(s_ + 512, d_ + 4096); } while (0)
#define STAGE_B3(h, tk, u) do { \
        const unsigned short* s_ = bT + (h) * 262144 + (tk) * 8192 + srcOff; \
        unsigned short* d_ = &lds[(u) * 32768 + 16384 + (h) * 8192 + wq]; \
        gload_lds16(s_, d_); gload_lds16(s_ + 512, d_ + 4096); } while (0)

    // ---- fragment read offsets (elements, chunk-major blocks): block m at m*512,
    //      within block: g*128 + cl*8; khalf at +4096; buffer at +u*32768 ----
    int rdA = wm * 8192 + g * 128 + cl * 8;
    int rdB = 16384 + (wn >> 1) * 8192 + (wn & 1) * 2048 + g * 128 + cl * 8;

    f32x4 acc[8][4] = {};
    short8 af[4][2], bf0[2][2], bf1[2][2];

    // prologue: tile0 fully + tile1 {B0,B1,A0}  (A1(1) staged at t=0)
    STAGE_A3(0, 0, 0); STAGE_B3(0, 0, 0); STAGE_B3(1, 0, 0); STAGE_A3(1, 0, 0);
    STAGE_B3(0, 1, 1); STAGE_B3(1, 1, 1); STAGE_A3(0, 1, 1);
    asm volatile("s_waitcnt vmcnt(6)" ::: "memory");   // tile0 landed; tile1's {B0,B1,A0} in flight
    BAR3();

    for (int t = 0; t < 32; ++t) {
        int u = t & 1;
        int ub = u * 32768;
        int tn = (t + 1) & 31, tnn = (t + 2) & 31;   // tail wraps: stages dead-but-safe data

        // ---- reads of regions that get overwritten mid-tile (A0, B0, B1 of buf u) ----
#pragma unroll
        for (int m = 0; m < 4; ++m) {
            af[m][0] = *(const short8*)&lds[ub + rdA + m * 512];
            af[m][1] = *(const short8*)&lds[ub + rdA + 4096 + m * 512];
        }
#pragma unroll
        for (int n = 0; n < 2; ++n) {
            bf0[n][0] = *(const short8*)&lds[ub + rdB + n * 512];
            bf0[n][1] = *(const short8*)&lds[ub + rdB + 4096 + n * 512];
        }
#pragma unroll
        for (int n = 0; n < 2; ++n) {
            bf1[n][0] = *(const short8*)&lds[ub + rdB + (n + 2) * 512];
            bf1[n][1] = *(const short8*)&lds[ub + rdB + 4096 + (n + 2) * 512];
        }
        STAGE_A3(1, tn, u ^ 1);        // A1(t+1); that region last read mid-tile t-1 (sep by bar b)
        BAR3();                        // bar (a): reads above done issuing before overwrites below

        // ===== Q0: mf0-3 x nf0-1, Q1: mf0-3 x nf2-3 =====
        __builtin_amdgcn_s_setprio(1);
#pragma unroll
        for (int h = 0; h < 2; ++h)
#pragma unroll
            for (int m = 0; m < 4; ++m)
#pragma unroll
                for (int n = 0; n < 2; ++n)
                    acc[m][n] = __builtin_amdgcn_mfma_f32_16x16x32_bf16(af[m][h], bf0[n][h], acc[m][n], 0, 0, 0);
#pragma unroll
        for (int h = 0; h < 2; ++h)
#pragma unroll
            for (int m = 0; m < 4; ++m)
#pragma unroll
                for (int n = 0; n < 2; ++n)
                    acc[m][n + 2] = __builtin_amdgcn_mfma_f32_16x16x32_bf16(af[m][h], bf1[n][h], acc[m][n + 2], 0, 0, 0);
        __builtin_amdgcn_s_setprio(0);

        // ---- overwrite staging for tile t+2 (regions read before bar a) ----
        STAGE_B3(0, tnn, u);
        STAGE_B3(1, tnn, u);
        STAGE_A3(0, tnn, u);

        // ---- A1 reads (region never overwritten mid-tile; WAR on af keeps them after Q1) ----
#pragma unroll
        for (int m = 0; m < 4; ++m) {
            af[m][0] = *(const short8*)&lds[ub + rdA + (m + 4) * 512];
            af[m][1] = *(const short8*)&lds[ub + rdA + 4096 + (m + 4) * 512];
        }

        // ===== Q2: mf4-7 x nf2-3, Q3: mf4-7 x nf0-1 =====
        __builtin_amdgcn_s_setprio(1);
#pragma unroll
        for (int h = 0; h < 2; ++h)
#pragma unroll
            for (int m = 0; m < 4; ++m)
#pragma unroll
                for (int n = 0; n < 2; ++n)
                    acc[m + 4][n + 2] = __builtin_amdgcn_mfma_f32_16x16x32_bf16(af[m][h], bf1[n][h], acc[m + 4][n + 2], 0, 0, 0);
#pragma unroll
        for (int h = 0; h < 2; ++h)
#pragma unroll
            for (int m = 0; m < 4; ++m)
#pragma unroll
                for (int n = 0; n < 2; ++n)
                    acc[m + 4][n] = __builtin_amdgcn_mfma_f32_16x16x32_bf16(af[m][h], bf0[n][h], acc[m + 4][n], 0, 0, 0);
        __builtin_amdgcn_s_setprio(0);

        asm volatile("s_waitcnt vmcnt(6)" ::: "memory");  // retires tile t+1's 4 half-tiles
        BAR3();                        // bar (b): globalize staging-complete
    }
#undef STAGE_A3
#undef STAGE_B3

    // ===== epilogue: p = exp(tanh(acc + t2)), store P bf16, rowsum reduce =====
    asm volatile("s_waitcnt vmcnt(0)" ::: "memory");
    __syncthreads();

    float t2v[4]; int ecol[4];
#pragma unroll
    for (int n = 0; n < 4; ++n) { ecol[n] = n0 + wn * 64 + n * 16 + cl; t2v[n] = t2[b * D_ + ecol[n]]; }
    int orow0 = b * L_ + j0 + wm * 128;
    int qd = g;

    float rs[8][4] = {};
#pragma unroll
    for (int m = 0; m < 8; ++m) {
        int lrowb = m * 16 + qd * 4;
#pragma unroll
        for (int n = 0; n < 4; ++n) {
#pragma unroll
            for (int gg = 0; gg < 4; ++gg) {
                float p = fast_pexp(acc[m][n][gg] + t2v[n]);
                rs[m][gg] += p;
                P[(size_t)(orow0 + lrowb + gg) * D_ + ecol[n]] = f2bf(p);
            }
        }
    }
#pragma unroll
    for (int m = 0; m < 8; ++m)
#pragma unroll
        for (int gg = 0; gg < 4; ++gg) {
            float v = rs[m][gg];
            v += __shfl_xor(v, 1); v += __shfl_xor(v, 2);
            v += __shfl_xor(v, 4); v += __shfl_xor(v, 8);
            rs[m][gg] = v;
        }
    float* red = (float*)lds;
    if (tid < 256) red[tid] = 0.f;
    __syncthreads();
    if (cl == 0) {
#pragma unroll
        for (int m = 0; m < 8; ++m)
#pragma unroll
            for (int gg = 0; gg < 4; ++gg)
                atomicAdd(&red[wm * 128 + m * 16 + qd * 4 + gg], rs[m][gg]);
    }
    __syncthreads();
    if (tid < 256) atomicAdd(&rowsum[b * L_ + j0 + tid], red[tid]);
}

// ---------------- v2 finale: out[b,e] = (sum_j P/rowsum + cnt0/2048) * trig_a ----------------
__global__ __launch_bounds__(256) void k_fin2(const unsigned short* __restrict__ P,
                                              const float* __restrict__ rowsum,
                                              const int* __restrict__ cnt1,
                                              const int* __restrict__ trigger,
                                              const float* __restrict__ hs,
                                              const float* __restrict__ xx,
                                              float* __restrict__ out) {
    int b = blockIdx.y;
    __shared__ float iv[L_];
    int n1 = cnt1[b];
    int lceil = (n1 + 127) & ~127;
    for (int j = threadIdx.x; j < L_; j += 256)
        iv[j] = (j < n1) ? 1.f / rowsum[b * L_ + j] : 0.f;
    __syncthreads();
    int e0 = blockIdx.x * 512 + threadIdx.x * 2;
    const unsigned short* Pb = P + (((size_t)b) << 20) + e0;
    float s0 = 0.f, s1 = 0.f;
#pragma unroll 8
    for (int l = 0; l < lceil; ++l) {
        float f = iv[l];
        u32 pv = *(const u32*)(Pb + (((size_t)l) << 11));
        s0 += f * bf2f(pv & 0xffffu);
        s1 += f * bf2f(pv >> 16);
    }
    float base = (float)(L_ - n1) * (1.f / 2048.f);
    int trig = trigger[b];
    size_t tb = ((size_t)(b * L_ + trig)) << 10;
    float ta0 = (e0 < 1024) ? hs[tb + e0] : xx[tb + e0 - 1024];
    float ta1 = (e0 + 1 < 1024) ? hs[tb + e0 + 1] : xx[tb + e0 + 1 - 1024];
    out[b * D_ + e0]     = (s0 + base) * ta0;
    out[b * D_ + e0 + 1] = (s1 + base) * ta1;
}

// ================= v1 fallback kernels (round-4, proven; float-A path only) =================
#define BM 128
#define BN 128
#define BK 32
#define LDK 40
__global__ __launch_bounds__(256) void k_gemm(
    const float* __restrict__ hs, const float* __restrict__ xx,
    const float* __restrict__ Wa, const unsigned short* __restrict__ Wb,
    const float* __restrict__ t2,
    const int* __restrict__ ridx, const int* __restrict__ cnt1,
    float* __restrict__ rowsum,
    unsigned short* __restrict__ P, float* __restrict__ out, int mode)
{
    __shared__ unsigned short Asl[BM][LDK];
    __shared__ unsigned short Bsl[BN][BK];
    __shared__ float red[BM];

    int tid = threadIdx.x;
    int lane = tid & 63;
    int w = tid >> 6;
    int wm = w & 1, wn = w >> 1;

    int n0 = blockIdx.x * BN;
    int jt = blockIdx.y;
    int b = jt >> 2;
    int j0 = (jt & 3) * BM;
    int n1 = cnt1[b];
    if (j0 >= n1) return;

    int r = tid >> 1;
    int koff = (tid & 1) * 16;
    int l = ridx[b * L_ + j0 + r];
    size_t abase = ((size_t)b * L_ + l) * (size_t)H_;
    const float* hrow = hs + abase;
    const float* xrow = xx + abase;
    const float* browf = Wa + (size_t)(n0 + r) * D_;

    f32x4 acc[4][4] = {};

    for (int k0 = 0; k0 < D_; k0 += BK) {
        int k = k0 + koff;
        const float* ap = (k < H_) ? (hrow + k) : (xrow + (k - H_));
        float4 a0 = *(const float4*)(ap);
        float4 a1 = *(const float4*)(ap + 4);
        float4 a2 = *(const float4*)(ap + 8);
        float4 a3 = *(const float4*)(ap + 12);
        const float* bp = browf + k;
        float4 c0 = *(const float4*)(bp);
        float4 c1 = *(const float4*)(bp + 4);
        float4 c2 = *(const float4*)(bp + 8);
        float4 c3 = *(const float4*)(bp + 12);
        __syncthreads();
        *(uint4*)&Asl[r][koff]     = make_uint4(pk(a0.x,a0.y), pk(a0.z,a0.w), pk(a1.x,a1.y), pk(a1.z,a1.w));
        *(uint4*)&Asl[r][koff + 8] = make_uint4(pk(a2.x,a2.y), pk(a2.z,a2.w), pk(a3.x,a3.y), pk(a3.z,a3.w));
        *(uint4*)&Bsl[r][koff]     = make_uint4(pk(c0.x,c0.y), pk(c0.z,c0.w), pk(c1.x,c1.y), pk(c1.z,c1.w));
        *(uint4*)&Bsl[r][koff + 8] = make_uint4(pk(c2.x,c2.y), pk(c2.z,c2.w), pk(c3.x,c3.y), pk(c3.z,c3.w));
        __syncthreads();
        int kb = (lane >> 4) * 8;
        short8 af[4], bfg[4];
#pragma unroll
        for (int i = 0; i < 4; ++i) af[i]  = *(const short8*)&Asl[wm*64 + i*16 + (lane & 15)][kb];
#pragma unroll
        for (int j = 0; j < 4; ++j) bfg[j] = *(const short8*)&Bsl[wn*64 + j*16 + (lane & 15)][kb];
#pragma unroll
        for (int i = 0; i < 4; ++i)
#pragma unroll
            for (int j = 0; j < 4; ++j)
                acc[i][j] = __builtin_amdgcn_mfma_f32_16x16x32_bf16(af[i], bfg[j], acc[i][j], 0, 0, 0);
    }

    int cl = lane & 15, qd = lane >> 4;
    float t2v[4]; int ecol[4];
#pragma unroll
    for (int j = 0; j < 4; ++j) { ecol[j] = n0 + wn*64 + j*16 + cl; t2v[j] = t2[b * D_ + ecol[j]]; }
    int orow0 = b * L_ + j0;

    if (mode <= 1) {
        float rs[4][4] = {};
#pragma unroll
        for (int i = 0; i < 4; ++i) {
            int lrowb = wm*64 + i*16 + qd*4;
#pragma unroll
            for (int j = 0; j < 4; ++j) {
#pragma unroll
                for (int g = 0; g < 4; ++g) {
                    float p = fast_pexp(acc[i][j][g] + t2v[j]);
                    rs[i][g] += p;
                    if (mode == 0)
                        P[(size_t)(orow0 + lrowb + g) * D_ + ecol[j]] = f2bf(p);
                }
            }
        }
#pragma unroll
        for (int i = 0; i < 4; ++i)
#pragma unroll
            for (int g = 0; g < 4; ++g) {
                float v = rs[i][g];
                v += __shfl_xor(v, 1); v += __shfl_xor(v, 2);
                v += __shfl_xor(v, 4); v += __shfl_xor(v, 8);
                rs[i][g] = v;
            }
        __syncthreads();
        if (tid < BM) red[tid] = 0.f;
        __syncthreads();
        if (cl == 0) {
#pragma unroll
            for (int i = 0; i < 4; ++i)
#pragma unroll
                for (int g = 0; g < 4; ++g)
                    atomicAdd(&red[wm*64 + i*16 + qd*4 + g], rs[i][g]);
        }
        __syncthreads();
        if (tid < BM) atomicAdd(&rowsum[orow0 + tid], red[tid]);
    } else {
        float inv[4][4];
#pragma unroll
        for (int i = 0; i < 4; ++i)
#pragma unroll
            for (int g = 0; g < 4; ++g) {
                int lrow = wm*64 + i*16 + qd*4 + g;
                inv[i][g] = (j0 + lrow < n1) ? (1.f / rowsum[orow0 + lrow]) : 0.f;
            }
        float cs[4] = {};
#pragma unroll
        for (int i = 0; i < 4; ++i)
#pragma unroll
            for (int j = 0; j < 4; ++j)
#pragma unroll
                for (int g = 0; g < 4; ++g)
                    cs[j] += fast_pexp(acc[i][j][g] + t2v[j]) * inv[i][g];
#pragma unroll
        for (int j = 0; j < 4; ++j) {
            float v = cs[j];
            v += __shfl_xor(v, 16); v += __shfl_xor(v, 32);
            cs[j] = v;
        }
        __syncthreads();
        if (tid < BN) red[tid] = 0.f;
        __syncthreads();
        if (qd == 0) {
#pragma unroll
            for (int j = 0; j < 4; ++j) atomicAdd(&red[wn*64 + j*16 + cl], cs[j]);
        }
        __syncthreads();
        if (tid < BN) atomicAdd(&out[b * D_ + n0 + tid], red[tid]);
    }
}

__global__ __launch_bounds__(256) void k_inv(const int* __restrict__ cnt1,
                                             const float* __restrict__ rowsum,
                                             float* __restrict__ invr) {
    int t = blockIdx.x * 256 + threadIdx.x;
    int b = t >> 9, j = t & 511;
    invr[t] = (j < cnt1[b]) ? (1.f / rowsum[t]) : 0.f;
}

__global__ __launch_bounds__(256) void k_fin(const unsigned short* __restrict__ P,
                                             const float* __restrict__ invr,
                                             const int* __restrict__ cnt1,
                                             float* __restrict__ out) {
    int b = blockIdx.y;
    int lz = blockIdx.z * 128;
    if (lz >= cnt1[b]) return;
    int e0 = blockIdx.x * 512 + threadIdx.x * 2;
    const unsigned short* Pb = P + ((size_t)b * L_ + lz) * D_ + e0;
    const float* ivb = invr + b * L_ + lz;
    float s0 = 0.f, s1 = 0.f;
    for (int l = 0; l < 128; ++l) {
        float iv = ivb[l];
        u32 pv = *(const u32*)(Pb + (size_t)l * D_);
        s0 += iv * bf2f(pv & 0xffffu);
        s1 += iv * bf2f(pv >> 16);
    }
    atomicAdd(&out[b * D_ + e0], s0);
    atomicAdd(&out[b * D_ + e0 + 1], s1);
}

__global__ __launch_bounds__(256) void k_final(
    const float* __restrict__ hs, const float* __restrict__ xx,
    const int* __restrict__ trigger, const float* __restrict__ cnt0,
    float* __restrict__ out) {
    int t = blockIdx.x * 256 + threadIdx.x;
    int b = t >> 11, e = t & 2047;
    int trig = trigger[b];
    size_t base = ((size_t)b * L_ + trig) * 1024;
    float ta = (e < 1024) ? hs[base + e] : xx[base + e - 1024];
    out[t] = (out[t] + cnt0[b] * (1.0f / 2048.0f)) * ta;
}

extern "C" void kernel_launch(void* const* d_in, const int* in_sizes, int n_in,
                              void* d_out, int out_size, void* d_ws, size_t ws_size,
                              hipStream_t stream) {
    const float* hs = (const float*)d_in[0];
    const float* xx = (const float*)d_in[1];
    const float* Wa = (const float*)d_in[2];
    const float* ba = (const float*)d_in[3];
    const float* Ws = (const float*)d_in[4];
    const float* bs = (const float*)d_in[5];
    const int*   trig = (const int*)d_in[6];
    const int*   mask = (const int*)d_in[7];
    float* out = (float*)d_out;

    float* wsf    = (float*)d_ws;
    float* s      = wsf;                 // 65536
    float* t2     = s + 65536;           // 131072
    float* cnt0   = t2 + 131072;         // 64
    float* rowsum = cnt0 + 64;           // 32768
    float* invr   = rowsum + 32768;      // 32768 (v1 only)
    int*   cnt1   = (int*)(invr + 32768);// 64
    int*   ridx   = cnt1 + 64;           // 32768
    unsigned short* P   = (unsigned short*)(ridx + 32768);   // 134,217,728 B @ 1,180,160
    unsigned short* Wb  = P + (size_t)B_ * L_ * D_;          //   8,388,608 B
    unsigned short* Abf = Wb + (size_t)D_ * D_;              // 134,217,728 B

    const size_t BASE_B   = 1180160ull;
    const size_t NEED_P   = BASE_B + 134217728ull;
    const size_t NEED_WB  = NEED_P + 8388608ull;
    const size_t NEED_ALL = NEED_WB + 134217728ull;          // ~278 MB
    bool haveP   = ws_size >= NEED_P;
    bool haveAll = ws_size >= NEED_ALL;

    (void)hipMemsetAsync(rowsum, 0, (size_t)B_ * L_ * sizeof(float), stream);

    k_s      <<<256, 256, 0, stream>>>(hs, s);
    k_compact<<<B_, 256, 0, stream>>>(mask, ba, bs, ridx, cnt1, cnt0, t2);
    k_t2     <<<dim3(32, 4), 256, 0, stream>>>(s, Ws, t2);

    if (haveAll) {
        // v6: 256^2 MFMA GEMM, contiguous-staging pre-tiled layout,
        // 2-barrier K-tile, XCD-local grid, counted-vmcnt staging
        k_cvtW <<<2048, 256, 0, stream>>>(Wa, Wb);
        k_prep <<<dim3(512, 64), 256, 0, stream>>>(hs, xx, ridx, cnt1, Abf);
        k_gemm3<<<dim3(128, 8), 512, 0, stream>>>(Abf, Wb, t2, cnt1, rowsum, P);
        k_fin2 <<<dim3(4, 64), 256, 0, stream>>>(P, rowsum, cnt1, trig, hs, xx, out);
    } else {
        dim3 grid(D_ / BN, (B_ * L_) / BM);   // 16 x 256 (blocks past cnt1 self-exit)
        (void)hipMemsetAsync(out, 0, (size_t)B_ * D_ * sizeof(float), stream);
        if (haveP) {
            k_gemm<<<grid, 256, 0, stream>>>(hs, xx, Wa, nullptr, t2, ridx, cnt1, rowsum, P, out, 0);
            k_inv <<<(B_ * L_) / 256, 256, 0, stream>>>(cnt1, rowsum, invr);
            k_fin <<<dim3(4, 64, 4), 256, 0, stream>>>(P, invr, cnt1, out);
        } else {
            k_gemm<<<grid, 256, 0, stream>>>(hs, xx, Wa, nullptr, t2, ridx, cnt1, rowsum, P, out, 1);
            k_gemm<<<grid, 256, 0, stream>>>(hs, xx, Wa, nullptr, t2, ridx, cnt1, rowsum, P, out, 2);
        }
        k_final<<<(B_ * D_) / 256, 256, 0, stream>>>(hs, xx, trig, cnt0, out);
    }
}